// Round 21
// baseline (6740.353 us; speedup 1.0000x reference)
//
#include <hip/hip_runtime.h>
#include <hip/hip_bf16.h>
#include <stdint.h>

#define DM 1024
#define DF 4096
#define NE 8
#define TT 16384
#define MAXTILES 264          // 128-row tiles
#define CAP (MAXTILES * 128)  // 33792 padded rows max

typedef __bf16 bf16;
typedef __attribute__((ext_vector_type(8))) __bf16 bf16x8;
typedef __attribute__((ext_vector_type(4))) __bf16 bf16x4;
typedef __attribute__((ext_vector_type(4))) float f32x4;

#define AS1 __attribute__((address_space(1)))
#define AS3 __attribute__((address_space(3)))

__device__ __forceinline__ void async16(void* lds, const void* g) {
  __builtin_amdgcn_global_load_lds((const AS1 uint32_t*)g, (AS3 uint32_t*)lds, 16, 0, 0);
}

// ---------------- router: logits + top2 + softmax2 (pure f32, exact) --------
__global__ void k_gate(const float* __restrict__ x, const float* __restrict__ gw,
                       const float* __restrict__ gb,
                       int* __restrict__ sel, float* __restrict__ cw) {
  int gid = blockIdx.x * blockDim.x + threadIdx.x;
  int tok = gid >> 6;
  int lane = threadIdx.x & 63;
  const float* xr = x + (size_t)tok * DM;
  float l[8] = {0,0,0,0,0,0,0,0};
#pragma unroll
  for (int i = 0; i < DM / 64; i++) {
    int d = i * 64 + lane;
    float xv = xr[d];
    float4 gA = *(const float4*)(gw + d * 8);
    float4 gB = *(const float4*)(gw + d * 8 + 4);
    l[0] += xv * gA.x; l[1] += xv * gA.y; l[2] += xv * gA.z; l[3] += xv * gA.w;
    l[4] += xv * gB.x; l[5] += xv * gB.y; l[6] += xv * gB.z; l[7] += xv * gB.w;
  }
#pragma unroll
  for (int e = 0; e < 8; e++) {
    float v = l[e];
    v += __shfl_xor(v, 1);  v += __shfl_xor(v, 2);  v += __shfl_xor(v, 4);
    v += __shfl_xor(v, 8);  v += __shfl_xor(v, 16); v += __shfl_xor(v, 32);
    l[e] = v + gb[e];
  }
  if (lane == 0) {
    int e0 = 0;
#pragma unroll
    for (int e = 1; e < 8; e++) if (l[e] > l[e0]) e0 = e;
    int e1 = (e0 == 0) ? 1 : 0;
#pragma unroll
    for (int e = 0; e < 8; e++) if (e != e1 && e != e0 && l[e] > l[e1]) e1 = e;
    float t = expf(l[e1] - l[e0]);      // <= 1
    float c0 = 1.0f / (1.0f + t);
    float c1 = t / (1.0f + t);
    sel[2 * tok] = e0;  sel[2 * tok + 1] = e1;
    cw[2 * tok] = c0;   cw[2 * tok + 1] = c1;
  }
}

// per-block LDS histogram over sel -> 8 global atomics per block
__global__ void k_hist(const int* __restrict__ sel, int* __restrict__ meta) {
  __shared__ int h[8];
  if (threadIdx.x < 8) h[threadIdx.x] = 0;
  __syncthreads();
  int i = blockIdx.x * blockDim.x + threadIdx.x;   // over 2*TT entries
  atomicAdd(&h[sel[i]], 1);
  __syncthreads();
  if (threadIdx.x < 8) atomicAdd(&meta[threadIdx.x], h[threadIdx.x]);
}

// meta layout (ints): [0..7]=counts [8..15]=cursors [16..23]=segment offsets
//                     [24]=ntiles [25]=total_padded
//                     [64 .. 64+MAXTILES)  = tile expert id
//                     [64+MAXTILES .. )    = tile row0 (padded global row)
__global__ void k_plan(int* __restrict__ meta, int* __restrict__ rows) {
  if (threadIdx.x == 0) {
    int off = 0, nt = 0;
    for (int e = 0; e < NE; e++) {
      meta[16 + e] = off;
      int c = meta[e];
      int ntile = (c + 127) >> 7;
      for (int j = 0; j < ntile; j++) {
        meta[64 + nt] = e;
        meta[64 + MAXTILES + nt] = off + j * 128;
        nt++;
      }
      off += ntile * 128;
    }
    meta[24] = nt;
    meta[25] = off;
  }
  __syncthreads();
  for (int i = threadIdx.x; i < CAP; i += blockDim.x) rows[i] = -1;
}

// 128 tokens/block; LDS-rank + 8 global atomics per block
__global__ void k_scatter(const int* __restrict__ sel, const float* __restrict__ cw,
                          int* __restrict__ meta, int* __restrict__ rows,
                          float* __restrict__ coefs) {
  __shared__ int hcnt[8];
  __shared__ int hbase[8];
  if (threadIdx.x < 8) hcnt[threadIdx.x] = 0;
  __syncthreads();
  int slot = blockIdx.x * 256 + threadIdx.x;   // (token,k) slot over 2*TT
  int t = slot >> 1;
  int e = sel[slot];
  int r = atomicAdd(&hcnt[e], 1);
  __syncthreads();
  if (threadIdx.x < 8) hbase[threadIdx.x] = atomicAdd(&meta[8 + threadIdx.x], hcnt[threadIdx.x]);
  __syncthreads();
  int pos = meta[16 + e] + hbase[e] + r;
  rows[pos] = t;
  coefs[pos] = cw[slot];
}

__global__ void k_gather(const float* __restrict__ x, const int* __restrict__ rows,
                         const int* __restrict__ meta, bf16* __restrict__ xg) {
  int pos = blockIdx.x;
  if (pos >= meta[25]) return;
  int t = rows[pos];
  int c = threadIdx.x * 4;
  bf16x4 o;
  if (t >= 0) {
    float4 f = *(const float4*)(x + (size_t)t * DM + c);
    o[0] = (bf16)f.x; o[1] = (bf16)f.y; o[2] = (bf16)f.z; o[3] = (bf16)f.w;
  } else {
    o[0] = (bf16)0.0f; o[1] = (bf16)0.0f; o[2] = (bf16)0.0f; o[3] = (bf16)0.0f;
  }
  *(bf16x4*)(xg + (size_t)pos * DM + c) = o;
}

// reads src[z*srcE + (r0+r)*srcRS + c0+c]  -> dst[z*dstE + (c0+c)*R + r0+r] bf16
__global__ void k_transcast(const float* __restrict__ src, bf16* __restrict__ dst,
                            int srcRS, size_t srcE, size_t dstE, int R) {
  __shared__ float tile[64][65];
  src += blockIdx.z * srcE;
  dst += blockIdx.z * dstE;
  int r0 = blockIdx.y * 64, c0 = blockIdx.x * 64;
  int tr = threadIdx.x >> 4;          // 0..15
  int tc = (threadIdx.x & 15) * 4;    // 0..60
#pragma unroll
  for (int i = 0; i < 4; i++) {
    int r = tr + i * 16;
    float4 f = *(const float4*)(src + (size_t)(r0 + r) * srcRS + (c0 + tc));
    tile[r][tc] = f.x; tile[r][tc + 1] = f.y; tile[r][tc + 2] = f.z; tile[r][tc + 3] = f.w;
  }
  __syncthreads();
#pragma unroll
  for (int i = 0; i < 4; i++) {
    int cc = tr + i * 16;             // output row = input col
    bf16x4 o;
    o[0] = (bf16)tile[tc + 0][cc];
    o[1] = (bf16)tile[tc + 1][cc];
    o[2] = (bf16)tile[tc + 2][cc];
    o[3] = (bf16)tile[tc + 3][cc];
    *(bf16x4*)(dst + (size_t)(c0 + cc) * R + (r0 + tc)) = o;
  }
}

// grouped GEMM: BM=BN=128, BK=32; 256 threads = 4 waves (2M x 2N),
// per-wave 64x64 = acc[4][4] (16 AGPR + ~44 VGPR ~= 60 unified, fits the
// 8-wave class cap of 64). SINGLE-buffer 16 KiB LDS + __launch_bounds__
// (256,8) -> target 8 blocks/CU (8x16 KiB = 128 KiB <= 160).
// R19/R20 A/B series: co-resident blocks are the lever (1/2/4 blocks ->
// 17K/8.5K/6.7K cyc per round); R20 showed the 8-wave class requires
// TOTAL (VGPR+AGPR) <= 64 or it spills -> BK=32 shrinks af/bfr/addressing
// to fit. Plain __syncthreads drain (m97 shape). Per K-tile:
//   {syncthreads; 4 gll; syncthreads; 8 ds_read; 16 MFMA}.
// T2 swizzle (4 k-chunks): LDS k-chunk c of row r holds global chunk
// c^(r&3); staged linearly from pre-swizzled source; read
// kx = ((lane>>4)^(lane&3))*8. Residual 4-way ds_read conflict accepted
// (1.58x on a non-critical pipe, m136).
// T1 bijective XCD swizzle (gsz=min(4,ngx) n-blocks share A-panels).
// MODE 0: H = silu(acc+bias) bf16;  MODE 1: atomicAdd(out, coef*(acc+bias))
template<int MODE>
__global__ __launch_bounds__(256, 8) void k_gemm(
    const bf16* __restrict__ A, const bf16* __restrict__ Bw,
    const float* __restrict__ bias, int bstride,
    bf16* __restrict__ H, float* __restrict__ Out, int addBias,
    const int* __restrict__ rows, const float* __restrict__ coefs,
    const int* __restrict__ meta, int KT, int NT) {
  int T = meta[24];
  int ngx = NT >> 7;                 // 128-wide n-blocks
  int nact = ngx * T;
  int b = blockIdx.x;
  if (b >= nact) return;
  // invert hardware RR -> contiguous per-XCD chunk (bijective, m204)
  int q = nact >> 3, rr = nact & 7;
  int xcd = b & 7, i = b >> 3;
  int j = xcd * q + (xcd < rr ? xcd : rr) + i;
  int gsz = (ngx < 4) ? ngx : 4;     // n-blocks per A-sharing group
  int gT = T * gsz;
  int g = j / gT;
  int rem = j - g * gT;
  int tidb = rem / gsz;              // tile index (contiguous within chunk)
  int xnb = g * gsz + (rem - tidb * gsz);
  int e = meta[64 + tidb];
  int row0 = meta[64 + MAXTILES + tidb];
  int n0 = xnb << 7;

  __shared__ __align__(16) bf16 As[128 * 32];   // 8 KiB
  __shared__ __align__(16) bf16 Bs[128 * 32];   // 8 KiB

  int t = threadIdx.x;              // 0..255
  int lane = t & 63;
  int w = t >> 6;                   // 0..3
  int wm = w >> 1, wn = w & 1;      // 2M x 2N

  // staging: thread t -> base row t>>2 (0..63), k-chunk t&3; covers rows
  // arow, arow+64 (differ by 64 == 0 mod 4, one pre-swizzled k8 serves both).
  int arow = t >> 2;
  int k8 = ((t & 3) ^ (arow & 3)) * 8;
  const bf16* Ab = A + (size_t)(row0 + arow) * KT + k8;
  const bf16* Bb = Bw + ((size_t)e * NT + n0 + arow) * KT + k8;
  size_t rstep = (size_t)64 * KT;
  int ldso = t * 8;                 // LDS elem offset (linear identity)

  f32x4 acc[4][4] = {};

  auto stage = [&](int kt) {
    const bf16* a = Ab + kt;
    const bf16* bb = Bb + kt;
    bf16* la = &As[ldso];
    bf16* lb = &Bs[ldso];
    async16(la,        a);                      // A rows arow, arow+64
    async16(la + 2048, a + rstep);
    async16(lb,        bb);                     // B rows arow, arow+64
    async16(lb + 2048, bb + rstep);
  };

  int rA = (wm * 64 + (lane & 15)) * 32;   // wave A base row * 32
  int rB = (wn * 64 + (lane & 15)) * 32;   // wave B base row * 32
  int kx = (((lane >> 4) ^ (lane & 3)) * 8);

  int nt = KT >> 5;                 // BK=32
  for (int tau = 0; tau < nt; ++tau) {
    __syncthreads();                 // all waves done reading previous tile
    stage(tau << 5);
    __syncthreads();                 // compiler drains vmcnt before barrier
    bf16x8 af[4], bfr[4];
#pragma unroll
    for (int ni = 0; ni < 4; ni++) bfr[ni] = *(const bf16x8*)&Bs[rB + ni * 512 + kx];
#pragma unroll
    for (int mi = 0; mi < 4; mi++) af[mi] = *(const bf16x8*)&As[rA + mi * 512 + kx];
#pragma unroll
    for (int mi = 0; mi < 4; mi++)
#pragma unroll
      for (int ni = 0; ni < 4; ni++)
        acc[mi][ni] = __builtin_amdgcn_mfma_f32_16x16x32_bf16(
            af[mi], bfr[ni], acc[mi][ni], 0, 0, 0);
  }

  int rq = (lane >> 4) * 4;
  int cq = lane & 15;
  float bv[4];
#pragma unroll
  for (int ni = 0; ni < 4; ni++)
    bv[ni] = bias[e * bstride + n0 + wn * 64 + ni * 16 + cq];

  if (MODE == 0) {
#pragma unroll
    for (int mi = 0; mi < 4; mi++) {
#pragma unroll
      for (int i2 = 0; i2 < 4; i2++) {
        int gr = row0 + wm * 64 + mi * 16 + rq + i2;
        bf16* hr = H + (size_t)gr * NT + n0 + wn * 64;
#pragma unroll
        for (int ni = 0; ni < 4; ni++) {
          float v = acc[mi][ni][i2] + bv[ni];
          float sg = v / (1.0f + __expf(-v));
          hr[ni * 16 + cq] = (bf16)sg;
        }
      }
    }
  } else {
#pragma unroll
    for (int mi = 0; mi < 4; mi++) {
#pragma unroll
      for (int i2 = 0; i2 < 4; i2++) {
        int gr = row0 + wm * 64 + mi * 16 + rq + i2;
        int trow = rows[gr];
        if (trow < 0) continue;
        float cf = coefs[gr];
        float* orow = Out + (size_t)trow * DM + n0 + wn * 64;
#pragma unroll
        for (int ni = 0; ni < 4; ni++) {
          float v = acc[mi][ni][i2];
          if (addBias) v += bv[ni];
          atomicAdd(&orow[ni * 16 + cq], cf * v);
        }
      }
    }
  }
}

extern "C" void kernel_launch(void* const* d_in, const int* in_sizes, int n_in,
                              void* d_out, int out_size, void* d_ws, size_t ws_size,
                              hipStream_t stream) {
  const float* x  = (const float*)d_in[0];
  const float* gw = (const float*)d_in[1];
  const float* gb = (const float*)d_in[2];
  const float* w1 = (const float*)d_in[3];
  const float* b1 = (const float*)d_in[4];
  const float* w2 = (const float*)d_in[5];
  const float* b2 = (const float*)d_in[6];
  float* out = (float*)d_out;

  // pick DF chunking so the workspace plan fits ws_size
  size_t smallB = (size_t)CAP * 4 * 2 + (size_t)TT * 2 * 4 * 2 + 8192 + 16 * 256;
  int nc = 8;
  for (int cand = 1; cand <= 8; cand <<= 1) {
    size_t dfc = DF / cand;
    size_t need = 2 * ((size_t)NE * dfc * DM * 2)   // w1tc + w2tc
                + (size_t)CAP * DM * 2              // xg
                + (size_t)CAP * dfc * 2             // h
                + smallB;
    if (need <= ws_size) { nc = cand; break; }
  }
  const int DFC = DF / nc;

  char* ws = (char*)d_ws;
  size_t off = 0;
  auto alloc = [&](size_t bytes) -> void* {
    void* p = ws + off;
    off += (bytes + 255) & ~(size_t)255;
    return p;
  };
  bf16* w1tc = (bf16*)alloc((size_t)NE * DFC * DM * 2);  // [E][DFC][DM]
  bf16* w2tc = (bf16*)alloc((size_t)NE * DM * DFC * 2);  // [E][DM][DFC]
  bf16* xg   = (bf16*)alloc((size_t)CAP * DM * 2);
  bf16* h    = (bf16*)alloc((size_t)CAP * DFC * 2);
  int* rows  = (int*)alloc((size_t)CAP * 4);
  float* cof = (float*)alloc((size_t)CAP * 4);
  int* sel   = (int*)alloc((size_t)TT * 2 * 4);
  float* cw  = (float*)alloc((size_t)TT * 2 * 4);
  int* meta  = (int*)alloc(8192);

  hipMemsetAsync(meta, 0, 256, stream);
  hipMemsetAsync(out, 0, (size_t)out_size * sizeof(float), stream);
  k_gate<<<TT / 4, 256, 0, stream>>>(x, gw, gb, sel, cw);
  k_hist<<<2 * TT / 256, 256, 0, stream>>>(sel, meta);
  k_plan<<<1, 256, 0, stream>>>(meta, rows);
  k_scatter<<<2 * TT / 256, 256, 0, stream>>>(sel, cw, meta, rows, cof);
  k_gather<<<CAP, 256, 0, stream>>>(x, rows, meta, xg);

  for (int c = 0; c < nc; c++) {
    const float* w1c = w1 + (size_t)c * DFC;        // [E][DM][DF] cols c*DFC..
    const float* w2c = w2 + (size_t)c * DFC * DM;   // [E][DF][DM] rows c*DFC..
    k_transcast<<<dim3(DFC / 64, DM / 64, NE), 256, 0, stream>>>(
        w1c, w1tc, DF, (size_t)DM * DF, (size_t)DFC * DM, DM);
    k_transcast<<<dim3(DM / 64, DFC / 64, NE), 256, 0, stream>>>(
        w2c, w2tc, DM, (size_t)DF * DM, (size_t)DM * DFC, DFC);
    // GEMM1: xg [CAP x DM] @ w1tc^T -> h (silu), N=DFC
    k_gemm<0><<<(DFC / 128) * MAXTILES, 256, 0, stream>>>(
        xg, w1tc, b1 + (size_t)c * DFC, DF, h, nullptr, 0, rows, cof, meta, DM, DFC);
    // GEMM2: h [CAP x DFC] @ w2tc^T -> atomic out, N=DM
    k_gemm<1><<<(DM / 128) * MAXTILES, 256, 0, stream>>>(
        h, w2tc, b2, DM, nullptr, out, (c == 0) ? 1 : 0, rows, cof, meta, DFC, DM);
  }
}

// Round 22
// 830.798 us; speedup vs baseline: 8.1131x; 8.1131x over previous
//
#include <hip/hip_runtime.h>
#include <hip/hip_bf16.h>
#include <stdint.h>

#define DM 1024
#define DF 4096
#define NE 8
#define TT 16384
#define MAXTILES 264          // 128-row tiles
#define CAP (MAXTILES * 128)  // 33792 padded rows max

typedef __bf16 bf16;
typedef __attribute__((ext_vector_type(8))) __bf16 bf16x8;
typedef __attribute__((ext_vector_type(4))) __bf16 bf16x4;
typedef __attribute__((ext_vector_type(4))) float f32x4;

#define AS1 __attribute__((address_space(1)))
#define AS3 __attribute__((address_space(3)))

__device__ __forceinline__ void async16(void* lds, const void* g) {
  __builtin_amdgcn_global_load_lds((const AS1 uint32_t*)g, (AS3 uint32_t*)lds, 16, 0, 0);
}

// ---------------- router: logits + top2 + softmax2 (pure f32, exact) --------
__global__ void k_gate(const float* __restrict__ x, const float* __restrict__ gw,
                       const float* __restrict__ gb,
                       int* __restrict__ sel, float* __restrict__ cw) {
  int gid = blockIdx.x * blockDim.x + threadIdx.x;
  int tok = gid >> 6;
  int lane = threadIdx.x & 63;
  const float* xr = x + (size_t)tok * DM;
  float l[8] = {0,0,0,0,0,0,0,0};
#pragma unroll
  for (int i = 0; i < DM / 64; i++) {
    int d = i * 64 + lane;
    float xv = xr[d];
    float4 gA = *(const float4*)(gw + d * 8);
    float4 gB = *(const float4*)(gw + d * 8 + 4);
    l[0] += xv * gA.x; l[1] += xv * gA.y; l[2] += xv * gA.z; l[3] += xv * gA.w;
    l[4] += xv * gB.x; l[5] += xv * gB.y; l[6] += xv * gB.z; l[7] += xv * gB.w;
  }
#pragma unroll
  for (int e = 0; e < 8; e++) {
    float v = l[e];
    v += __shfl_xor(v, 1);  v += __shfl_xor(v, 2);  v += __shfl_xor(v, 4);
    v += __shfl_xor(v, 8);  v += __shfl_xor(v, 16); v += __shfl_xor(v, 32);
    l[e] = v + gb[e];
  }
  if (lane == 0) {
    int e0 = 0;
#pragma unroll
    for (int e = 1; e < 8; e++) if (l[e] > l[e0]) e0 = e;
    int e1 = (e0 == 0) ? 1 : 0;
#pragma unroll
    for (int e = 0; e < 8; e++) if (e != e1 && e != e0 && l[e] > l[e1]) e1 = e;
    float t = expf(l[e1] - l[e0]);      // <= 1
    float c0 = 1.0f / (1.0f + t);
    float c1 = t / (1.0f + t);
    sel[2 * tok] = e0;  sel[2 * tok + 1] = e1;
    cw[2 * tok] = c0;   cw[2 * tok + 1] = c1;
  }
}

// per-block LDS histogram over sel -> 8 global atomics per block
__global__ void k_hist(const int* __restrict__ sel, int* __restrict__ meta) {
  __shared__ int h[8];
  if (threadIdx.x < 8) h[threadIdx.x] = 0;
  __syncthreads();
  int i = blockIdx.x * blockDim.x + threadIdx.x;   // over 2*TT entries
  atomicAdd(&h[sel[i]], 1);
  __syncthreads();
  if (threadIdx.x < 8) atomicAdd(&meta[threadIdx.x], h[threadIdx.x]);
}

// meta layout (ints): [0..7]=counts [8..15]=cursors [16..23]=segment offsets
//                     [24]=ntiles [25]=total_padded
//                     [64 .. 64+MAXTILES)  = tile expert id
//                     [64+MAXTILES .. )    = tile row0 (padded global row)
__global__ void k_plan(int* __restrict__ meta, int* __restrict__ rows) {
  if (threadIdx.x == 0) {
    int off = 0, nt = 0;
    for (int e = 0; e < NE; e++) {
      meta[16 + e] = off;
      int c = meta[e];
      int ntile = (c + 127) >> 7;
      for (int j = 0; j < ntile; j++) {
        meta[64 + nt] = e;
        meta[64 + MAXTILES + nt] = off + j * 128;
        nt++;
      }
      off += ntile * 128;
    }
    meta[24] = nt;
    meta[25] = off;
  }
  __syncthreads();
  for (int i = threadIdx.x; i < CAP; i += blockDim.x) rows[i] = -1;
}

// 128 tokens/block; LDS-rank + 8 global atomics per block
__global__ void k_scatter(const int* __restrict__ sel, const float* __restrict__ cw,
                          int* __restrict__ meta, int* __restrict__ rows,
                          float* __restrict__ coefs) {
  __shared__ int hcnt[8];
  __shared__ int hbase[8];
  if (threadIdx.x < 8) hcnt[threadIdx.x] = 0;
  __syncthreads();
  int slot = blockIdx.x * 256 + threadIdx.x;   // (token,k) slot over 2*TT
  int t = slot >> 1;
  int e = sel[slot];
  int r = atomicAdd(&hcnt[e], 1);
  __syncthreads();
  if (threadIdx.x < 8) hbase[threadIdx.x] = atomicAdd(&meta[8 + threadIdx.x], hcnt[threadIdx.x]);
  __syncthreads();
  int pos = meta[16 + e] + hbase[e] + r;
  rows[pos] = t;
  coefs[pos] = cw[slot];
}

__global__ void k_gather(const float* __restrict__ x, const int* __restrict__ rows,
                         const int* __restrict__ meta, bf16* __restrict__ xg) {
  int pos = blockIdx.x;
  if (pos >= meta[25]) return;
  int t = rows[pos];
  int c = threadIdx.x * 4;
  bf16x4 o;
  if (t >= 0) {
    float4 f = *(const float4*)(x + (size_t)t * DM + c);
    o[0] = (bf16)f.x; o[1] = (bf16)f.y; o[2] = (bf16)f.z; o[3] = (bf16)f.w;
  } else {
    o[0] = (bf16)0.0f; o[1] = (bf16)0.0f; o[2] = (bf16)0.0f; o[3] = (bf16)0.0f;
  }
  *(bf16x4*)(xg + (size_t)pos * DM + c) = o;
}

// reads src[z*srcE + (r0+r)*srcRS + c0+c]  -> dst[z*dstE + (c0+c)*R + r0+r] bf16
__global__ void k_transcast(const float* __restrict__ src, bf16* __restrict__ dst,
                            int srcRS, size_t srcE, size_t dstE, int R) {
  __shared__ float tile[64][65];
  src += blockIdx.z * srcE;
  dst += blockIdx.z * dstE;
  int r0 = blockIdx.y * 64, c0 = blockIdx.x * 64;
  int tr = threadIdx.x >> 4;          // 0..15
  int tc = (threadIdx.x & 15) * 4;    // 0..60
#pragma unroll
  for (int i = 0; i < 4; i++) {
    int r = tr + i * 16;
    float4 f = *(const float4*)(src + (size_t)(r0 + r) * srcRS + (c0 + tc));
    tile[r][tc] = f.x; tile[r][tc + 1] = f.y; tile[r][tc + 2] = f.z; tile[r][tc + 3] = f.w;
  }
  __syncthreads();
#pragma unroll
  for (int i = 0; i < 4; i++) {
    int cc = tr + i * 16;             // output row = input col
    bf16x4 o;
    o[0] = (bf16)tile[tc + 0][cc];
    o[1] = (bf16)tile[tc + 1][cc];
    o[2] = (bf16)tile[tc + 2][cc];
    o[3] = (bf16)tile[tc + 3][cc];
    *(bf16x4*)(dst + (size_t)(c0 + cc) * R + (r0 + tc)) = o;
  }
}

// grouped GEMM: BM=BN=128, BK=64; 256 threads = 4 waves (2M x 2N),
// per-wave 64x64 = acc[4][4] (measured 64 VGPR). SINGLE-buffer 32 KiB LDS +
// __launch_bounds__(256,4) -> 4 blocks/CU. R19-R21 A/B series: co-resident
// blocks are the lever (m114 cross-block overlap; 1/2/4 blocks -> 17K/8.5K/
// 6.7K cyc per round); >4 waves/SIMD requests force the 64-total register
// class -> scratch spill (R20: 48 VGPR + 1.3GB WRITE; R21: 32 VGPR + 9GB).
// This config is the measured optimum (369 us/GEMM, ~767 TF, MfmaUtil 33%).
// Plain __syncthreads drain (m97 shape, compiler emits vmcnt drain + fine
// lgkmcnt). Per K-tile: {syncthreads; 8 gll; syncthreads; 2x(8 dsr+16 MFMA)}.
// T2 swizzle (verified 0-conflict family): LDS k-chunk c of row r holds
// global chunk c^(r&7); staged linearly from pre-swizzled source; read
// kx = ((lane>>4)^(lane&7))*8 (+32 for ks1).
// T1 bijective XCD swizzle (gsz=min(4,ngx) n-blocks share A-panels).
// MODE 0: H = silu(acc+bias) bf16;  MODE 1: atomicAdd(out, coef*(acc+bias))
template<int MODE>
__global__ __launch_bounds__(256, 4) void k_gemm(
    const bf16* __restrict__ A, const bf16* __restrict__ Bw,
    const float* __restrict__ bias, int bstride,
    bf16* __restrict__ H, float* __restrict__ Out, int addBias,
    const int* __restrict__ rows, const float* __restrict__ coefs,
    const int* __restrict__ meta, int KT, int NT) {
  int T = meta[24];
  int ngx = NT >> 7;                 // 128-wide n-blocks
  int nact = ngx * T;
  int b = blockIdx.x;
  if (b >= nact) return;
  // invert hardware RR -> contiguous per-XCD chunk (bijective, m204)
  int q = nact >> 3, rr = nact & 7;
  int xcd = b & 7, i = b >> 3;
  int j = xcd * q + (xcd < rr ? xcd : rr) + i;
  int gsz = (ngx < 4) ? ngx : 4;     // n-blocks per A-sharing group
  int gT = T * gsz;
  int g = j / gT;
  int rem = j - g * gT;
  int tidb = rem / gsz;              // tile index (contiguous within chunk)
  int xnb = g * gsz + (rem - tidb * gsz);
  int e = meta[64 + tidb];
  int row0 = meta[64 + MAXTILES + tidb];
  int n0 = xnb << 7;

  __shared__ __align__(16) bf16 As[128 * 64];   // 16 KiB
  __shared__ __align__(16) bf16 Bs[128 * 64];   // 16 KiB

  int t = threadIdx.x;              // 0..255
  int lane = t & 63;
  int w = t >> 6;                   // 0..3
  int wm = w >> 1, wn = w & 1;      // 2M x 2N

  // staging: thread t -> base row t>>3 (0..31), k-chunk t&7; rows +0/32/64/96
  // differ by 32 == 0 mod 8, so one pre-swizzled k8 serves all chunks.
  int arow = t >> 3;
  int k8 = ((t & 7) ^ (arow & 7)) * 8;
  const bf16* Ab = A + (size_t)(row0 + arow) * KT + k8;
  const bf16* Bb = Bw + ((size_t)e * NT + n0 + arow) * KT + k8;
  size_t rstep = (size_t)32 * KT;
  int ldso = t * 8;                 // LDS elem offset (linear identity)

  f32x4 acc[4][4] = {};

  auto stage = [&](int kt) {
    const bf16* a = Ab + kt;
    const bf16* bb = Bb + kt;
    bf16* la = &As[ldso];
    bf16* lb = &Bs[ldso];
    async16(la,        a);                      // A rows arow+{0,32,64,96}
    async16(la + 2048, a + rstep);
    async16(la + 4096, a + 2 * rstep);
    async16(la + 6144, a + 3 * rstep);
    async16(lb,        bb);                     // B rows arow+{0,32,64,96}
    async16(lb + 2048, bb + rstep);
    async16(lb + 4096, bb + 2 * rstep);
    async16(lb + 6144, bb + 3 * rstep);
  };

  int rA = (wm * 64 + (lane & 15)) * 64;   // wave A base row * 64
  int rB = (wn * 64 + (lane & 15)) * 64;   // wave B base row * 64
  int kx0 = ((lane >> 4) * 8) ^ ((lane & 7) * 8);
  int kx1 = kx0 ^ 32;

  int nt = KT >> 6;
  for (int tau = 0; tau < nt; ++tau) {
    __syncthreads();                 // all waves done reading previous tile
    stage(tau << 6);
    __syncthreads();                 // compiler drains vmcnt before barrier
    const bf16* Ap = &As[rA];
    const bf16* Bp = &Bs[rB];
    {
      bf16x8 af[4], bfr[4];
#pragma unroll
      for (int ni = 0; ni < 4; ni++) bfr[ni] = *(const bf16x8*)&Bp[ni * 1024 + kx0];
#pragma unroll
      for (int mi = 0; mi < 4; mi++) af[mi] = *(const bf16x8*)&Ap[mi * 1024 + kx0];
#pragma unroll
      for (int mi = 0; mi < 4; mi++)
#pragma unroll
        for (int ni = 0; ni < 4; ni++)
          acc[mi][ni] = __builtin_amdgcn_mfma_f32_16x16x32_bf16(
              af[mi], bfr[ni], acc[mi][ni], 0, 0, 0);
    }
    {
      bf16x8 af[4], bfr[4];
#pragma unroll
      for (int ni = 0; ni < 4; ni++) bfr[ni] = *(const bf16x8*)&Bp[ni * 1024 + kx1];
#pragma unroll
      for (int mi = 0; mi < 4; mi++) af[mi] = *(const bf16x8*)&Ap[mi * 1024 + kx1];
#pragma unroll
      for (int mi = 0; mi < 4; mi++)
#pragma unroll
        for (int ni = 0; ni < 4; ni++)
          acc[mi][ni] = __builtin_amdgcn_mfma_f32_16x16x32_bf16(
              af[mi], bfr[ni], acc[mi][ni], 0, 0, 0);
    }
  }

  int rq = (lane >> 4) * 4;
  int cq = lane & 15;
  float bv[4];
#pragma unroll
  for (int ni = 0; ni < 4; ni++)
    bv[ni] = bias[e * bstride + n0 + wn * 64 + ni * 16 + cq];

  if (MODE == 0) {
#pragma unroll
    for (int mi = 0; mi < 4; mi++) {
#pragma unroll
      for (int i2 = 0; i2 < 4; i2++) {
        int gr = row0 + wm * 64 + mi * 16 + rq + i2;
        bf16* hr = H + (size_t)gr * NT + n0 + wn * 64;
#pragma unroll
        for (int ni = 0; ni < 4; ni++) {
          float v = acc[mi][ni][i2] + bv[ni];
          float sg = v / (1.0f + __expf(-v));
          hr[ni * 16 + cq] = (bf16)sg;
        }
      }
    }
  } else {
#pragma unroll
    for (int mi = 0; mi < 4; mi++) {
#pragma unroll
      for (int i2 = 0; i2 < 4; i2++) {
        int gr = row0 + wm * 64 + mi * 16 + rq + i2;
        int trow = rows[gr];
        if (trow < 0) continue;
        float cf = coefs[gr];
        float* orow = Out + (size_t)trow * DM + n0 + wn * 64;
#pragma unroll
        for (int ni = 0; ni < 4; ni++) {
          float v = acc[mi][ni][i2];
          if (addBias) v += bv[ni];
          atomicAdd(&orow[ni * 16 + cq], cf * v);
        }
      }
    }
  }
}

extern "C" void kernel_launch(void* const* d_in, const int* in_sizes, int n_in,
                              void* d_out, int out_size, void* d_ws, size_t ws_size,
                              hipStream_t stream) {
  const float* x  = (const float*)d_in[0];
  const float* gw = (const float*)d_in[1];
  const float* gb = (const float*)d_in[2];
  const float* w1 = (const float*)d_in[3];
  const float* b1 = (const float*)d_in[4];
  const float* w2 = (const float*)d_in[5];
  const float* b2 = (const float*)d_in[6];
  float* out = (float*)d_out;

  // pick DF chunking so the workspace plan fits ws_size
  size_t smallB = (size_t)CAP * 4 * 2 + (size_t)TT * 2 * 4 * 2 + 8192 + 16 * 256;
  int nc = 8;
  for (int cand = 1; cand <= 8; cand <<= 1) {
    size_t dfc = DF / cand;
    size_t need = 2 * ((size_t)NE * dfc * DM * 2)   // w1tc + w2tc
                + (size_t)CAP * DM * 2              // xg
                + (size_t)CAP * dfc * 2             // h
                + smallB;
    if (need <= ws_size) { nc = cand; break; }
  }
  const int DFC = DF / nc;

  char* ws = (char*)d_ws;
  size_t off = 0;
  auto alloc = [&](size_t bytes) -> void* {
    void* p = ws + off;
    off += (bytes + 255) & ~(size_t)255;
    return p;
  };
  bf16* w1tc = (bf16*)alloc((size_t)NE * DFC * DM * 2);  // [E][DFC][DM]
  bf16* w2tc = (bf16*)alloc((size_t)NE * DM * DFC * 2);  // [E][DM][DFC]
  bf16* xg   = (bf16*)alloc((size_t)CAP * DM * 2);
  bf16* h    = (bf16*)alloc((size_t)CAP * DFC * 2);
  int* rows  = (int*)alloc((size_t)CAP * 4);
  float* cof = (float*)alloc((size_t)CAP * 4);
  int* sel   = (int*)alloc((size_t)TT * 2 * 4);
  float* cw  = (float*)alloc((size_t)TT * 2 * 4);
  int* meta  = (int*)alloc(8192);

  hipMemsetAsync(meta, 0, 256, stream);
  hipMemsetAsync(out, 0, (size_t)out_size * sizeof(float), stream);
  k_gate<<<TT / 4, 256, 0, stream>>>(x, gw, gb, sel, cw);
  k_hist<<<2 * TT / 256, 256, 0, stream>>>(sel, meta);
  k_plan<<<1, 256, 0, stream>>>(meta, rows);
  k_scatter<<<2 * TT / 256, 256, 0, stream>>>(sel, cw, meta, rows, cof);
  k_gather<<<CAP, 256, 0, stream>>>(x, rows, meta, xg);

  for (int c = 0; c < nc; c++) {
    const float* w1c = w1 + (size_t)c * DFC;        // [E][DM][DF] cols c*DFC..
    const float* w2c = w2 + (size_t)c * DFC * DM;   // [E][DF][DM] rows c*DFC..
    k_transcast<<<dim3(DFC / 64, DM / 64, NE), 256, 0, stream>>>(
        w1c, w1tc, DF, (size_t)DM * DF, (size_t)DFC * DM, DM);
    k_transcast<<<dim3(DM / 64, DFC / 64, NE), 256, 0, stream>>>(
        w2c, w2tc, DM, (size_t)DF * DM, (size_t)DM * DFC, DFC);
    // GEMM1: xg [CAP x DM] @ w1tc^T -> h (silu), N=DFC
    k_gemm<0><<<(DFC / 128) * MAXTILES, 256, 0, stream>>>(
        xg, w1tc, b1 + (size_t)c * DFC, DF, h, nullptr, 0, rows, cof, meta, DM, DFC);
    // GEMM2: h [CAP x DFC] @ w2tc^T -> atomic out, N=DM
    k_gemm<1><<<(DM / 128) * MAXTILES, 256, 0, stream>>>(
        h, w2tc, b2, DM, nullptr, out, (c == 0) ? 1 : 0, rows, cof, meta, DFC, DM);
  }
}

// Round 23
// 822.028 us; speedup vs baseline: 8.1997x; 1.0107x over previous
//
#include <hip/hip_runtime.h>
#include <hip/hip_bf16.h>
#include <stdint.h>

#define DM 1024
#define DF 4096
#define NE 8
#define TT 16384
#define MAXTILES 264          // 128-row tiles
#define CAP (MAXTILES * 128)  // 33792 padded rows max

typedef __bf16 bf16;
typedef __attribute__((ext_vector_type(8))) __bf16 bf16x8;
typedef __attribute__((ext_vector_type(4))) __bf16 bf16x4;
typedef __attribute__((ext_vector_type(4))) float f32x4;

#define AS1 __attribute__((address_space(1)))
#define AS3 __attribute__((address_space(3)))

__device__ __forceinline__ void async16(void* lds, const void* g) {
  __builtin_amdgcn_global_load_lds((const AS1 uint32_t*)g, (AS3 uint32_t*)lds, 16, 0, 0);
}

// ---------------- router: logits + top2 + softmax2 (pure f32, exact) --------
__global__ void k_gate(const float* __restrict__ x, const float* __restrict__ gw,
                       const float* __restrict__ gb,
                       int* __restrict__ sel, float* __restrict__ cw) {
  int gid = blockIdx.x * blockDim.x + threadIdx.x;
  int tok = gid >> 6;
  int lane = threadIdx.x & 63;
  const float* xr = x + (size_t)tok * DM;
  float l[8] = {0,0,0,0,0,0,0,0};
#pragma unroll
  for (int i = 0; i < DM / 64; i++) {
    int d = i * 64 + lane;
    float xv = xr[d];
    float4 gA = *(const float4*)(gw + d * 8);
    float4 gB = *(const float4*)(gw + d * 8 + 4);
    l[0] += xv * gA.x; l[1] += xv * gA.y; l[2] += xv * gA.z; l[3] += xv * gA.w;
    l[4] += xv * gB.x; l[5] += xv * gB.y; l[6] += xv * gB.z; l[7] += xv * gB.w;
  }
#pragma unroll
  for (int e = 0; e < 8; e++) {
    float v = l[e];
    v += __shfl_xor(v, 1);  v += __shfl_xor(v, 2);  v += __shfl_xor(v, 4);
    v += __shfl_xor(v, 8);  v += __shfl_xor(v, 16); v += __shfl_xor(v, 32);
    l[e] = v + gb[e];
  }
  if (lane == 0) {
    int e0 = 0;
#pragma unroll
    for (int e = 1; e < 8; e++) if (l[e] > l[e0]) e0 = e;
    int e1 = (e0 == 0) ? 1 : 0;
#pragma unroll
    for (int e = 0; e < 8; e++) if (e != e1 && e != e0 && l[e] > l[e1]) e1 = e;
    float t = expf(l[e1] - l[e0]);      // <= 1
    float c0 = 1.0f / (1.0f + t);
    float c1 = t / (1.0f + t);
    sel[2 * tok] = e0;  sel[2 * tok + 1] = e1;
    cw[2 * tok] = c0;   cw[2 * tok + 1] = c1;
  }
}

// per-block LDS histogram over sel -> 8 global atomics per block
__global__ void k_hist(const int* __restrict__ sel, int* __restrict__ meta) {
  __shared__ int h[8];
  if (threadIdx.x < 8) h[threadIdx.x] = 0;
  __syncthreads();
  int i = blockIdx.x * blockDim.x + threadIdx.x;   // over 2*TT entries
  atomicAdd(&h[sel[i]], 1);
  __syncthreads();
  if (threadIdx.x < 8) atomicAdd(&meta[threadIdx.x], h[threadIdx.x]);
}

// meta layout (ints): [0..7]=counts [8..15]=cursors [16..23]=segment offsets
//                     [24]=ntiles [25]=total_padded
//                     [64 .. 64+MAXTILES)  = tile expert id
//                     [64+MAXTILES .. )    = tile row0 (padded global row)
__global__ void k_plan(int* __restrict__ meta, int* __restrict__ rows) {
  if (threadIdx.x == 0) {
    int off = 0, nt = 0;
    for (int e = 0; e < NE; e++) {
      meta[16 + e] = off;
      int c = meta[e];
      int ntile = (c + 127) >> 7;
      for (int j = 0; j < ntile; j++) {
        meta[64 + nt] = e;
        meta[64 + MAXTILES + nt] = off + j * 128;
        nt++;
      }
      off += ntile * 128;
    }
    meta[24] = nt;
    meta[25] = off;
  }
  __syncthreads();
  for (int i = threadIdx.x; i < CAP; i += blockDim.x) rows[i] = -1;
}

// 128 tokens/block; LDS-rank + 8 global atomics per block
__global__ void k_scatter(const int* __restrict__ sel, const float* __restrict__ cw,
                          int* __restrict__ meta, int* __restrict__ rows,
                          float* __restrict__ coefs) {
  __shared__ int hcnt[8];
  __shared__ int hbase[8];
  if (threadIdx.x < 8) hcnt[threadIdx.x] = 0;
  __syncthreads();
  int slot = blockIdx.x * 256 + threadIdx.x;   // (token,k) slot over 2*TT
  int t = slot >> 1;
  int e = sel[slot];
  int r = atomicAdd(&hcnt[e], 1);
  __syncthreads();
  if (threadIdx.x < 8) hbase[threadIdx.x] = atomicAdd(&meta[8 + threadIdx.x], hcnt[threadIdx.x]);
  __syncthreads();
  int pos = meta[16 + e] + hbase[e] + r;
  rows[pos] = t;
  coefs[pos] = cw[slot];
}

__global__ void k_gather(const float* __restrict__ x, const int* __restrict__ rows,
                         const int* __restrict__ meta, bf16* __restrict__ xg) {
  int pos = blockIdx.x;
  if (pos >= meta[25]) return;
  int t = rows[pos];
  int c = threadIdx.x * 4;
  bf16x4 o;
  if (t >= 0) {
    float4 f = *(const float4*)(x + (size_t)t * DM + c);
    o[0] = (bf16)f.x; o[1] = (bf16)f.y; o[2] = (bf16)f.z; o[3] = (bf16)f.w;
  } else {
    o[0] = (bf16)0.0f; o[1] = (bf16)0.0f; o[2] = (bf16)0.0f; o[3] = (bf16)0.0f;
  }
  *(bf16x4*)(xg + (size_t)pos * DM + c) = o;
}

// reads src[z*srcE + (r0+r)*srcRS + c0+c]  -> dst[z*dstE + (c0+c)*R + r0+r] bf16
__global__ void k_transcast(const float* __restrict__ src, bf16* __restrict__ dst,
                            int srcRS, size_t srcE, size_t dstE, int R) {
  __shared__ float tile[64][65];
  src += blockIdx.z * srcE;
  dst += blockIdx.z * dstE;
  int r0 = blockIdx.y * 64, c0 = blockIdx.x * 64;
  int tr = threadIdx.x >> 4;          // 0..15
  int tc = (threadIdx.x & 15) * 4;    // 0..60
#pragma unroll
  for (int i = 0; i < 4; i++) {
    int r = tr + i * 16;
    float4 f = *(const float4*)(src + (size_t)(r0 + r) * srcRS + (c0 + tc));
    tile[r][tc] = f.x; tile[r][tc + 1] = f.y; tile[r][tc + 2] = f.z; tile[r][tc + 3] = f.w;
  }
  __syncthreads();
#pragma unroll
  for (int i = 0; i < 4; i++) {
    int cc = tr + i * 16;             // output row = input col
    bf16x4 o;
    o[0] = (bf16)tile[tc + 0][cc];
    o[1] = (bf16)tile[tc + 1][cc];
    o[2] = (bf16)tile[tc + 2][cc];
    o[3] = (bf16)tile[tc + 3][cc];
    *(bf16x4*)(dst + (size_t)(c0 + cc) * R + (r0 + tc)) = o;
  }
}

// grouped GEMM: BM=BN=128, BK=64; 256 threads = 4 waves (2M x 2N),
// per-wave 64x64 = acc[4][4] (64 VGPR). SINGLE-buffer 32 KiB LDS +
// __launch_bounds__(256,4) -> 4 blocks/CU (measured optimum; >4 waves/SIMD
// forces the 64-total register class -> spill, R20/R21).
// R23 change: T1 group gsz 4 -> 8. Per-XCD co-resident set (128 blocks)
// spans 16 tiles x 8 n-blocks; distinct K-slice bytes per round =
// 16x16KB (A) + 8x16KB (B) = 384 KB (vs 576 KB at gsz=4), L2-resident ->
// FETCH (measured 450 MB, 40% miss of staged, ~80% of round time at
// ~10 B/cyc/CU) should drop ~33%.
// Plain __syncthreads drain (m97 shape). Per K-tile:
//   {syncthreads; 8 gll; syncthreads; 2x(8 dsr + 16 MFMA)}.
// T2 swizzle (verified 0-conflict family): LDS k-chunk c of row r holds
// global chunk c^(r&7); staged linearly from pre-swizzled source; read
// kx = ((lane>>4)^(lane&7))*8 (+32 for ks1).
// MODE 0: H = silu(acc+bias) bf16;  MODE 1: atomicAdd(out, coef*(acc+bias))
template<int MODE>
__global__ __launch_bounds__(256, 4) void k_gemm(
    const bf16* __restrict__ A, const bf16* __restrict__ Bw,
    const float* __restrict__ bias, int bstride,
    bf16* __restrict__ H, float* __restrict__ Out, int addBias,
    const int* __restrict__ rows, const float* __restrict__ coefs,
    const int* __restrict__ meta, int KT, int NT) {
  int T = meta[24];
  int ngx = NT >> 7;                 // 128-wide n-blocks
  int nact = ngx * T;
  int b = blockIdx.x;
  if (b >= nact) return;
  // invert hardware RR -> contiguous per-XCD chunk (bijective, m204)
  int q = nact >> 3, rr = nact & 7;
  int xcd = b & 7, i = b >> 3;
  int j = xcd * q + (xcd < rr ? xcd : rr) + i;
  int gsz = (ngx < 8) ? ngx : 8;     // n-blocks per A-sharing group (R23: 8)
  int gT = T * gsz;
  int g = j / gT;
  int rem = j - g * gT;
  int tidb = rem / gsz;              // tile index (contiguous within chunk)
  int xnb = g * gsz + (rem - tidb * gsz);
  int e = meta[64 + tidb];
  int row0 = meta[64 + MAXTILES + tidb];
  int n0 = xnb << 7;

  __shared__ __align__(16) bf16 As[128 * 64];   // 16 KiB
  __shared__ __align__(16) bf16 Bs[128 * 64];   // 16 KiB

  int t = threadIdx.x;              // 0..255
  int lane = t & 63;
  int w = t >> 6;                   // 0..3
  int wm = w >> 1, wn = w & 1;      // 2M x 2N

  // staging: thread t -> base row t>>3 (0..31), k-chunk t&7; rows +0/32/64/96
  // differ by 32 == 0 mod 8, so one pre-swizzled k8 serves all chunks.
  int arow = t >> 3;
  int k8 = ((t & 7) ^ (arow & 7)) * 8;
  const bf16* Ab = A + (size_t)(row0 + arow) * KT + k8;
  const bf16* Bb = Bw + ((size_t)e * NT + n0 + arow) * KT + k8;
  size_t rstep = (size_t)32 * KT;
  int ldso = t * 8;                 // LDS elem offset (linear identity)

  f32x4 acc[4][4] = {};

  auto stage = [&](int kt) {
    const bf16* a = Ab + kt;
    const bf16* bb = Bb + kt;
    bf16* la = &As[ldso];
    bf16* lb = &Bs[ldso];
    async16(la,        a);                      // A rows arow+{0,32,64,96}
    async16(la + 2048, a + rstep);
    async16(la + 4096, a + 2 * rstep);
    async16(la + 6144, a + 3 * rstep);
    async16(lb,        bb);                     // B rows arow+{0,32,64,96}
    async16(lb + 2048, bb + rstep);
    async16(lb + 4096, bb + 2 * rstep);
    async16(lb + 6144, bb + 3 * rstep);
  };

  int rA = (wm * 64 + (lane & 15)) * 64;   // wave A base row * 64
  int rB = (wn * 64 + (lane & 15)) * 64;   // wave B base row * 64
  int kx0 = ((lane >> 4) * 8) ^ ((lane & 7) * 8);
  int kx1 = kx0 ^ 32;

  int nt = KT >> 6;
  for (int tau = 0; tau < nt; ++tau) {
    __syncthreads();                 // all waves done reading previous tile
    stage(tau << 6);
    __syncthreads();                 // compiler drains vmcnt before barrier
    const bf16* Ap = &As[rA];
    const bf16* Bp = &Bs[rB];
    {
      bf16x8 af[4], bfr[4];
#pragma unroll
      for (int ni = 0; ni < 4; ni++) bfr[ni] = *(const bf16x8*)&Bp[ni * 1024 + kx0];
#pragma unroll
      for (int mi = 0; mi < 4; mi++) af[mi] = *(const bf16x8*)&Ap[mi * 1024 + kx0];
#pragma unroll
      for (int mi = 0; mi < 4; mi++)
#pragma unroll
        for (int ni = 0; ni < 4; ni++)
          acc[mi][ni] = __builtin_amdgcn_mfma_f32_16x16x32_bf16(
              af[mi], bfr[ni], acc[mi][ni], 0, 0, 0);
    }
    {
      bf16x8 af[4], bfr[4];
#pragma unroll
      for (int ni = 0; ni < 4; ni++) bfr[ni] = *(const bf16x8*)&Bp[ni * 1024 + kx1];
#pragma unroll
      for (int mi = 0; mi < 4; mi++) af[mi] = *(const bf16x8*)&Ap[mi * 1024 + kx1];
#pragma unroll
      for (int mi = 0; mi < 4; mi++)
#pragma unroll
        for (int ni = 0; ni < 4; ni++)
          acc[mi][ni] = __builtin_amdgcn_mfma_f32_16x16x32_bf16(
              af[mi], bfr[ni], acc[mi][ni], 0, 0, 0);
    }
  }

  int rq = (lane >> 4) * 4;
  int cq = lane & 15;
  float bv[4];
#pragma unroll
  for (int ni = 0; ni < 4; ni++)
    bv[ni] = bias[e * bstride + n0 + wn * 64 + ni * 16 + cq];

  if (MODE == 0) {
#pragma unroll
    for (int mi = 0; mi < 4; mi++) {
#pragma unroll
      for (int i2 = 0; i2 < 4; i2++) {
        int gr = row0 + wm * 64 + mi * 16 + rq + i2;
        bf16* hr = H + (size_t)gr * NT + n0 + wn * 64;
#pragma unroll
        for (int ni = 0; ni < 4; ni++) {
          float v = acc[mi][ni][i2] + bv[ni];
          float sg = v / (1.0f + __expf(-v));
          hr[ni * 16 + cq] = (bf16)sg;
        }
      }
    }
  } else {
#pragma unroll
    for (int mi = 0; mi < 4; mi++) {
#pragma unroll
      for (int i2 = 0; i2 < 4; i2++) {
        int gr = row0 + wm * 64 + mi * 16 + rq + i2;
        int trow = rows[gr];
        if (trow < 0) continue;
        float cf = coefs[gr];
        float* orow = Out + (size_t)trow * DM + n0 + wn * 64;
#pragma unroll
        for (int ni = 0; ni < 4; ni++) {
          float v = acc[mi][ni][i2];
          if (addBias) v += bv[ni];
          atomicAdd(&orow[ni * 16 + cq], cf * v);
        }
      }
    }
  }
}

extern "C" void kernel_launch(void* const* d_in, const int* in_sizes, int n_in,
                              void* d_out, int out_size, void* d_ws, size_t ws_size,
                              hipStream_t stream) {
  const float* x  = (const float*)d_in[0];
  const float* gw = (const float*)d_in[1];
  const float* gb = (const float*)d_in[2];
  const float* w1 = (const float*)d_in[3];
  const float* b1 = (const float*)d_in[4];
  const float* w2 = (const float*)d_in[5];
  const float* b2 = (const float*)d_in[6];
  float* out = (float*)d_out;

  // pick DF chunking so the workspace plan fits ws_size
  size_t smallB = (size_t)CAP * 4 * 2 + (size_t)TT * 2 * 4 * 2 + 8192 + 16 * 256;
  int nc = 8;
  for (int cand = 1; cand <= 8; cand <<= 1) {
    size_t dfc = DF / cand;
    size_t need = 2 * ((size_t)NE * dfc * DM * 2)   // w1tc + w2tc
                + (size_t)CAP * DM * 2              // xg
                + (size_t)CAP * dfc * 2             // h
                + smallB;
    if (need <= ws_size) { nc = cand; break; }
  }
  const int DFC = DF / nc;

  char* ws = (char*)d_ws;
  size_t off = 0;
  auto alloc = [&](size_t bytes) -> void* {
    void* p = ws + off;
    off += (bytes + 255) & ~(size_t)255;
    return p;
  };
  bf16* w1tc = (bf16*)alloc((size_t)NE * DFC * DM * 2);  // [E][DFC][DM]
  bf16* w2tc = (bf16*)alloc((size_t)NE * DM * DFC * 2);  // [E][DM][DFC]
  bf16* xg   = (bf16*)alloc((size_t)CAP * DM * 2);
  bf16* h    = (bf16*)alloc((size_t)CAP * DFC * 2);
  int* rows  = (int*)alloc((size_t)CAP * 4);
  float* cof = (float*)alloc((size_t)CAP * 4);
  int* sel   = (int*)alloc((size_t)TT * 2 * 4);
  float* cw  = (float*)alloc((size_t)TT * 2 * 4);
  int* meta  = (int*)alloc(8192);

  hipMemsetAsync(meta, 0, 256, stream);
  hipMemsetAsync(out, 0, (size_t)out_size * sizeof(float), stream);
  k_gate<<<TT / 4, 256, 0, stream>>>(x, gw, gb, sel, cw);
  k_hist<<<2 * TT / 256, 256, 0, stream>>>(sel, meta);
  k_plan<<<1, 256, 0, stream>>>(meta, rows);
  k_scatter<<<2 * TT / 256, 256, 0, stream>>>(sel, cw, meta, rows, cof);
  k_gather<<<CAP, 256, 0, stream>>>(x, rows, meta, xg);

  for (int c = 0; c < nc; c++) {
    const float* w1c = w1 + (size_t)c * DFC;        // [E][DM][DF] cols c*DFC..
    const float* w2c = w2 + (size_t)c * DFC * DM;   // [E][DF][DM] rows c*DFC..
    k_transcast<<<dim3(DFC / 64, DM / 64, NE), 256, 0, stream>>>(
        w1c, w1tc, DF, (size_t)DM * DF, (size_t)DFC * DM, DM);
    k_transcast<<<dim3(DM / 64, DFC / 64, NE), 256, 0, stream>>>(
        w2c, w2tc, DM, (size_t)DF * DM, (size_t)DM * DFC, DFC);
    // GEMM1: xg [CAP x DM] @ w1tc^T -> h (silu), N=DFC
    k_gemm<0><<<(DFC / 128) * MAXTILES, 256, 0, stream>>>(
        xg, w1tc, b1 + (size_t)c * DFC, DF, h, nullptr, 0, rows, cof, meta, DM, DFC);
    // GEMM2: h [CAP x DFC] @ w2tc^T -> atomic out, N=DM
    k_gemm<1><<<(DM / 128) * MAXTILES, 256, 0, stream>>>(
        h, w2tc, b2, DM, nullptr, out, (c == 0) ? 1 : 0, rows, cof, meta, DFC, DM);
  }
}